// Round 7
// baseline (184.311 us; speedup 1.0000x reference)
//
#include <hip/hip_runtime.h>

typedef short s16x8 __attribute__((ext_vector_type(8)));
typedef float f32x4 __attribute__((ext_vector_type(4)));
typedef float f32x16 __attribute__((ext_vector_type(16)));

#define B_ 4
#define C_ 256
#define S_ 4096
#define LOG2E 1.44269504088896f
#define M2 32.0f   // fixed base-2 softmax offset: p = 2^(s' - M2)

#if __has_builtin(__builtin_amdgcn_exp2f)
#define EXP2(x) __builtin_amdgcn_exp2f(x)
#else
#define EXP2(x) __exp2f(x)
#endif

// RNE float -> bf16
__device__ __forceinline__ unsigned short f2b(float f) {
  union { float f; unsigned u; } v; v.f = f;
  unsigned r = v.u + 0x7fffu + ((v.u >> 16) & 1u);
  return (unsigned short)(r >> 16);
}
// cheap round-half-up float -> bf16 (hot loop)
__device__ __forceinline__ unsigned short f2b_fast(float f) {
  union { float f; unsigned u; } v; v.f = f;
  return (unsigned short)((v.u + 0x8000u) >> 16);
}
// 16B LDS load at 8B alignment
__device__ __forceinline__ s16x8 lds_ld8(const unsigned short* p) {
  union { s16x8 v; uint2 u[2]; } r;
  r.u[0] = *(const uint2*)p;
  r.u[1] = *(const uint2*)(p + 4);
  return r.v;
}

// ---- weight prep: fp32 -> bf16 MFMA A-fragment order ------------------------
__global__ __launch_bounds__(256)
void prep_kernel(const float* __restrict__ wq, const float* __restrict__ wk,
                 const float* __restrict__ wv,
                 unsigned short* __restrict__ Wvf, unsigned short* __restrict__ Wqkf) {
  const int G = (blockIdx.x * 256 + threadIdx.x) * 4;
  union { unsigned short us[4]; uint2 u2; } pk;
  if (G < 65536) {
    const int e0 = G & 7, lane = (G >> 3) & 63, ks16 = (G >> 9) & 15;
    const int mt = (G >> 13) & 1, cg = G >> 14;
    const int row = cg * 64 + mt * 32 + (lane & 31);
    const int k   = ks16 * 16 + (lane >> 5) * 8 + e0;
    f32x4 v = *(const f32x4*)(wv + (size_t)row * 256 + k);
    #pragma unroll
    for (int i = 0; i < 4; ++i) pk.us[i] = f2b(v[i]);
    *(uint2*)(Wvf + G) = pk.u2;
  } else {
    const int H = G - 65536;
    const int e0 = H & 7, lane = (H >> 3) & 63, ks16 = (H >> 9) & 15;
    const int mt = (H >> 13) & 1;
    const int row = lane & 31;
    const int k   = ks16 * 16 + (lane >> 5) * 8 + e0;
    const float* src = mt ? wk : wq;
    f32x4 v = *(const f32x4*)(src + (size_t)row * 256 + k);
    if (mt == 0) v = v * LOG2E;
    #pragma unroll
    for (int i = 0; i < 4; ++i) pk.us[i] = f2b(v[i]);
    *(uint2*)(Wqkf + H) = pk.u2;
  }
}

// ---- Q/K projection (unchanged from r6) -------------------------------------
__global__ __launch_bounds__(256, 2)
void qkproj_kernel(const float* __restrict__ x,
                   const float* __restrict__ bq, const float* __restrict__ bk,
                   const unsigned short* __restrict__ Wqkf,
                   unsigned short* __restrict__ Qb, unsigned short* __restrict__ Kb) {
  __shared__ union {
    unsigned short Sl[64 * 260];
    unsigned short Rl[64 * 68];
  } um;
  const int jt = blockIdx.x, b = blockIdx.y;
  const int n0 = jt * 64;
  const int t = threadIdx.x;
  const int L = t & 63, w = t >> 6;
  const int g = L >> 5, l32 = L & 31;
  const float* xb = x + (size_t)b * C_ * S_;
  #pragma unroll
  for (int hp = 0; hp < 2; ++hp) {
    const int c8 = hp * 128 + (t >> 4) * 8;
    const int n4 = (t & 15) * 4;
    f32x4 v[8];
    #pragma unroll
    for (int j = 0; j < 8; ++j)
      v[j] = *(const f32x4*)(xb + (size_t)(c8 + j) * S_ + n0 + n4);
    #pragma unroll
    for (int k = 0; k < 4; ++k) {
      union { unsigned short us[8]; uint2 u2[2]; } pk;
      #pragma unroll
      for (int j = 0; j < 8; ++j) pk.us[j] = f2b(v[j][k]);
      *(uint2*)&um.Sl[(n4 + k) * 260 + c8]     = pk.u2[0];
      *(uint2*)&um.Sl[(n4 + k) * 260 + c8 + 4] = pk.u2[1];
    }
  }
  __syncthreads();
  const int mt = w >> 1, nt = w & 1;
  f32x16 acc = (f32x16)0.0f;
  #pragma unroll
  for (int ks = 0; ks < 16; ++ks) {
    s16x8 af = *(const s16x8*)(Wqkf + ((size_t)(mt * 16 + ks) * 64 + L) * 8);
    s16x8 bf = lds_ld8(&um.Sl[(nt * 32 + l32) * 260 + ks * 16 + g * 8]);
    acc = __builtin_amdgcn_mfma_f32_32x32x16_bf16(af, bf, acc, 0, 0, 0);
  }
  __syncthreads();
  const int n = nt * 32 + l32;
  #pragma unroll
  for (int reg = 0; reg < 16; ++reg) {
    const int rr = (reg & 3) + 8 * (reg >> 2) + 4 * g;
    const float val = (mt == 0) ? acc[reg] + bq[rr] * LOG2E : acc[reg] + bk[rr];
    um.Rl[n * 68 + mt * 32 + rr] = f2b(val);
  }
  __syncthreads();
  const int nn = t >> 2, ch0 = (t & 3) * 16;
  s16x8 a = lds_ld8(um.Rl + nn * 68 + ch0);
  s16x8 cvec = lds_ld8(um.Rl + nn * 68 + ch0 + 8);
  unsigned short* dst = (ch0 < 32)
      ? Qb + ((size_t)b * S_ + n0 + nn) * 32 + ch0
      : Kb + ((size_t)b * S_ + n0 + nn) * 32 + (ch0 - 32);
  *(s16x8*)dst = a;
  *(s16x8*)(dst + 8) = cvec;
}

// ---- V projection -----------------------------------------------------------
// grid (64 jt, 4 b), 512 threads. Produces Vf frag tiles for 128-j chunks:
// addr(shorts) = (((b*32+chunk)*2+chh)*4+cg)*4096 + kb*512 + (g8*32+(ch&31))*8 + e
// where within-chunk col = pi(jj) = (jj&15)*8 + (jj>>4); kb=col>>4, g8=(col>>3)&1,
// e=col&7; this 64-j block (jt parity) supplies e in {0..3} or {4..7}.
__global__ __launch_bounds__(512, 2)
void vproj_kernel(const float* __restrict__ orig, const float* __restrict__ bv,
                  const unsigned short* __restrict__ Wvf,
                  unsigned short* __restrict__ Vf) {
  __shared__ union {
    unsigned short Sl[64 * 260];   // [n][c] bf16
    unsigned short Rv[256 * 68];   // [ch][jl] repack (natural jl order)
  } um;
  const int jt = blockIdx.x, b = blockIdx.y;
  const int n0 = jt * 64;
  const int t = threadIdx.x;
  const int L = t & 63, w = t >> 6;
  const int g = L >> 5, l32 = L & 31;
  const float* ob = orig + (size_t)b * C_ * S_;
  {
    const int c8 = (t >> 4) * 8;
    const int n4 = (t & 15) * 4;
    f32x4 v[8];
    #pragma unroll
    for (int j = 0; j < 8; ++j)
      v[j] = *(const f32x4*)(ob + (size_t)(c8 + j) * S_ + n0 + n4);
    #pragma unroll
    for (int k = 0; k < 4; ++k) {
      union { unsigned short us[8]; uint2 u2[2]; } pk;
      #pragma unroll
      for (int j = 0; j < 8; ++j) pk.us[j] = f2b(v[j][k]);
      *(uint2*)&um.Sl[(n4 + k) * 260 + c8]     = pk.u2[0];
      *(uint2*)&um.Sl[(n4 + k) * 260 + c8 + 4] = pk.u2[1];
    }
  }
  __syncthreads();
  f32x16 acc0 = (f32x16)0.0f, acc1 = (f32x16)0.0f;
  #pragma unroll
  for (int ks = 0; ks < 16; ++ks) {
    s16x8 af  = *(const s16x8*)(Wvf + ((size_t)(w * 16 + ks) * 64 + L) * 8);
    s16x8 bf0 = lds_ld8(&um.Sl[l32 * 260 + ks * 16 + g * 8]);
    s16x8 bf1 = lds_ld8(&um.Sl[(32 + l32) * 260 + ks * 16 + g * 8]);
    acc0 = __builtin_amdgcn_mfma_f32_32x32x16_bf16(af, bf0, acc0, 0, 0, 0);
    acc1 = __builtin_amdgcn_mfma_f32_32x32x16_bf16(af, bf1, acc1, 0, 0, 0);
  }
  __syncthreads();
  const int chw = w * 32;
  #pragma unroll
  for (int reg = 0; reg < 16; ++reg) {
    const int rr = (reg & 3) + 8 * (reg >> 2) + 4 * g;
    const float bias = bv[chw + rr];
    um.Rv[(chw + rr) * 68 + l32]      = f2b(acc0[reg] + bias);
    um.Rv[(chw + rr) * 68 + 32 + l32] = f2b(acc1[reg] + bias);
  }
  __syncthreads();
  // pi-gather copy-out: 8 half-fragments (8B) per thread
  const int chunk = jt >> 1, par = jt & 1;
  #pragma unroll
  for (int k = 0; k < 8; ++k) {
    const int id = k * 512 + t;            // 0..4095 = (c16 4b)(ch 8b)
    const int c16v = id >> 8;              // 0..15
    const int ch = id & 255;
    union { unsigned short us[4]; uint2 u2; } pk;
    #pragma unroll
    for (int u = 0; u < 4; ++u)            // jl = u*16 + c16v
      pk.us[u] = um.Rv[ch * 68 + u * 16 + c16v];
    const int kb = c16v >> 1, g8 = c16v & 1;
    const size_t base = ((size_t)((b * 32 + chunk) * 2 + (ch >> 7)) * 4 + ((ch >> 5) & 3)) * 4096;
    *(uint2*)(Vf + base + kb * 512 + (g8 * 32 + (ch & 31)) * 8 + par * 4) = pk.u2;
  }
}

// ---- flash attention: i-tile 128, ch-split 2, 128-j chunks ------------------
// 512 threads, grid 256 (1 block/CU), one barrier per chunk.
// Phase A: wave rh=w owns rows rh*16..+16, full 128 j from K-LDS; p=exp2(s-M2),
//          pi-packed b32 -> P dbuf.  lp per-lane.
// Phase B: wave (cg=w&3, ih=w>>2) owns ch cg*32 (of this block's 128-ch half)
//          x i {ih*64, +32}; V frags straight from global (pre-swizzled).
struct FlashSmem {
  union {
    unsigned short P[2][128 * 132];   // 67584 B, dbuf, pi cols
    float scr[32 * 130];              // 16640 B, epilogue transpose
  } u;
  __align__(16) unsigned short Kl[2][128 * 40];  // 20480 B, 80B rows (pad)
  float lvec[128];
  float invl[128];
};

__global__ __launch_bounds__(512, 2)
void flash_kernel(const unsigned short* __restrict__ Qb,
                  const unsigned short* __restrict__ Kb,
                  const unsigned short* __restrict__ Vf,
                  const float* __restrict__ inp,
                  const float* __restrict__ gamma,
                  float* __restrict__ out) {
  __shared__ FlashSmem sm;
  const int l   = blockIdx.x;
  const int b   = (l & 7) >> 1;     // XCD <-> (b,chh): V-half resident in L2
  const int chh = l & 1;
  const int i0  = (l >> 3) * 128;
  const int ch0 = chh * 128;
  const int t = threadIdx.x;
  const int L = t & 63, w = t >> 6;
  const int q4 = L >> 4, c16 = L & 15;
  const int g  = L >> 5, l32 = L & 31;
  const int rh = w;                 // phase A
  const int cg = w & 3, ih = w >> 2; // phase B
  const float gam = gamma[0];
  const unsigned short* Kbb = Kb + (size_t)b * S_ * 32;
  const s16x8 qf = *(const s16x8*)(Qb + ((size_t)b * S_ + i0 + rh * 16 + c16) * 32 + q4 * 8);

  f32x16 acc0 = (f32x16)0.0f, acc1 = (f32x16)0.0f;  // i {ih*64, +32} x ch cg*32
  float lp[4] = {0.f, 0.f, 0.f, 0.f};

  // stage K chunk 0 (8 KB, padded 80B rows)
  *(s16x8*)&sm.Kl[0][(t >> 2) * 40 + (t & 3) * 8] = *(const s16x8*)(Kbb + t * 8);
  __syncthreads();

  for (int c = 0; c < 32; ++c) {
    // global loads at interval top
    s16x8 vf[8];
    if (c > 0) {
      const unsigned short* vb = Vf + ((size_t)((b * 32 + (c - 1)) * 2 + chh) * 4 + cg) * 4096;
      #pragma unroll
      for (int kb = 0; kb < 8; ++kb)
        vf[kb] = *(const s16x8*)(vb + kb * 512 + L * 8);
    }
    if (c < 31)
      *(s16x8*)&sm.Kl[(c + 1) & 1][(t >> 2) * 40 + (t & 3) * 8] =
          *(const s16x8*)(Kbb + (size_t)(c + 1) * 4096 + t * 8);
    // ---- Phase A(c)
    unsigned short* Pw = sm.u.P[c & 1];
    const unsigned short* Klc = sm.Kl[c & 1];
    #pragma unroll
    for (int u = 0; u < 4; ++u) {
      const s16x8 kf0 = *(const s16x8*)(Klc + ((2 * u + 0) * 16 + c16) * 40 + q4 * 8);
      const s16x8 kf1 = *(const s16x8*)(Klc + ((2 * u + 1) * 16 + c16) * 40 + q4 * 8);
      const f32x4 cinit = (f32x4)(-M2);
      f32x4 s0 = __builtin_amdgcn_mfma_f32_16x16x32_bf16(qf, kf0, cinit, 0, 0, 0);
      f32x4 s1 = __builtin_amdgcn_mfma_f32_16x16x32_bf16(qf, kf1, cinit, 0, 0, 0);
      #pragma unroll
      for (int r = 0; r < 4; ++r) {
        const float p0 = EXP2(s0[r]);
        const float p1 = EXP2(s1[r]);
        lp[r] += p0 + p1;
        const int row = rh * 16 + q4 * 4 + r;
        const unsigned pack = (unsigned)f2b_fast(p0) | ((unsigned)f2b_fast(p1) << 16);
        *(unsigned*)&Pw[row * 132 + c16 * 8 + 2 * u] = pack;   // pi cols
      }
    }
    // ---- Phase B(c-1)
    if (c > 0) {
      const unsigned short* Pr = sm.u.P[(c - 1) & 1];
      #pragma unroll
      for (int kb = 0; kb < 8; ++kb) {
        const int ko = kb * 16 + g * 8;
        const s16x8 pf0 = lds_ld8(Pr + (ih * 64 + l32) * 132 + ko);
        const s16x8 pf1 = lds_ld8(Pr + (ih * 64 + 32 + l32) * 132 + ko);
        acc0 = __builtin_amdgcn_mfma_f32_32x32x16_bf16(pf0, vf[kb], acc0, 0, 0, 0);
        acc1 = __builtin_amdgcn_mfma_f32_32x32x16_bf16(pf1, vf[kb], acc1, 0, 0, 0);
      }
    }
    __syncthreads();
  }
  // ---- tail: Phase B(31)
  {
    const unsigned short* vb = Vf + ((size_t)((b * 32 + 31) * 2 + chh) * 4 + cg) * 4096;
    s16x8 vf[8];
    #pragma unroll
    for (int kb = 0; kb < 8; ++kb)
      vf[kb] = *(const s16x8*)(vb + kb * 512 + L * 8);
    const unsigned short* Pr = sm.u.P[1];
    #pragma unroll
    for (int kb = 0; kb < 8; ++kb) {
      const int ko = kb * 16 + g * 8;
      const s16x8 pf0 = lds_ld8(Pr + (ih * 64 + l32) * 132 + ko);
      const s16x8 pf1 = lds_ld8(Pr + (ih * 64 + 32 + l32) * 132 + ko);
      acc0 = __builtin_amdgcn_mfma_f32_32x32x16_bf16(pf0, vf[kb], acc0, 0, 0, 0);
      acc1 = __builtin_amdgcn_mfma_f32_32x32x16_bf16(pf1, vf[kb], acc1, 0, 0, 0);
    }
  }
  // ---- l reduction (over the 16 c16-lanes; each wave covered full j)
  #pragma unroll
  for (int r = 0; r < 4; ++r) {
    float v = lp[r];
    #pragma unroll
    for (int d = 1; d < 16; d <<= 1) v += __shfl_xor(v, d, 64);
    lp[r] = v;
  }
  if (c16 == 0) {
    #pragma unroll
    for (int r = 0; r < 4; ++r) sm.lvec[rh * 16 + q4 * 4 + r] = lp[r];
  }
  __syncthreads();
  if (t < 128) sm.invl[t] = gam / sm.lvec[t];
  // ---- epilogue: 4 passes of 32 i; transpose via scr; +input; store
  #pragma unroll
  for (int h = 0; h < 4; ++h) {
    if (ih == (h >> 1)) {
      const f32x16 a = (h & 1) ? acc1 : acc0;
      #pragma unroll
      for (int reg = 0; reg < 16; ++reg) {
        const int rr = (reg & 3) + 8 * (reg >> 2) + 4 * g;
        sm.u.scr[rr * 130 + cg * 32 + l32] = a[reg];
      }
    }
    __syncthreads();   // scr ready (+ invl visible on first pass)
    const int ch = t >> 2;          // 0..127 (block-local)
    const int i4 = (t & 3) * 8;     // 0,8,16,24
    const f32x4 sc0 = *(const f32x4*)&sm.invl[h * 32 + i4];
    const f32x4 sc1 = *(const f32x4*)&sm.invl[h * 32 + i4 + 4];
    const size_t gi = ((size_t)(b * C_ + ch0 + ch)) * S_ + i0 + h * 32 + i4;
    const f32x4 in0 = *(const f32x4*)(inp + gi);
    const f32x4 in1 = *(const f32x4*)(inp + gi + 4);
    f32x4 o0, o1;
    #pragma unroll
    for (int k = 0; k < 4; ++k) {
      o0[k] = sm.u.scr[(i4 + k) * 130 + ch] * sc0[k] + in0[k];
      o1[k] = sm.u.scr[(i4 + 4 + k) * 130 + ch] * sc1[k] + in1[k];
    }
    *(f32x4*)(out + gi)     = o0;
    *(f32x4*)(out + gi + 4) = o1;
    __syncthreads();   // scr free for next pass
  }
}

// ---- launch -----------------------------------------------------------------
extern "C" void kernel_launch(void* const* d_in, const int* in_sizes, int n_in,
                              void* d_out, int out_size, void* d_ws, size_t ws_size,
                              hipStream_t stream) {
  const float* inp   = (const float*)d_in[0];
  const float* orig  = (const float*)d_in[1];
  const float* wq    = (const float*)d_in[2];
  const float* bq    = (const float*)d_in[3];
  const float* wk    = (const float*)d_in[4];
  const float* bk    = (const float*)d_in[5];
  const float* wv    = (const float*)d_in[6];
  const float* bv    = (const float*)d_in[7];
  const float* gamma = (const float*)d_in[8];
  float* out = (float*)d_out;

  unsigned short* Qb = (unsigned short*)d_ws;            // [B][S][32] bf16, 1 MB
  unsigned short* Kb = Qb + (size_t)B_ * S_ * 32;        // [B][S][32] bf16, 1 MB
  unsigned short* Vf = Kb + (size_t)B_ * S_ * 32;        // frag-tiled V, 8 MB
  // weight fragments in the tail of d_out (stream-ordered, race-free)
  unsigned short* Wvf  = (unsigned short*)((char*)d_out + (size_t)out_size * 4 - 262144);
  unsigned short* Wqkf = Wvf + 65536;

  prep_kernel<<<80, 256, 0, stream>>>(wq, wk, wv, Wvf, Wqkf);
  qkproj_kernel<<<dim3(64, 4), 256, 0, stream>>>(inp, bq, bk, Wqkf, Qb, Kb);
  vproj_kernel<<<dim3(64, 4), 512, 0, stream>>>(orig, bv, Wvf, Vf);
  flash_kernel<<<256, 512, 0, stream>>>(Qb, Kb, Vf, inp, gamma, out);
}